// Round 1
// 69.748 us; speedup vs baseline: 1.0502x; 1.0502x over previous
//
#include <hip/hip_runtime.h>

// Problem constants (B=64, IN=1024, UNITS=1024, BITS=8)
#define IN_F   1024
#define UNITS  1024
#define BDIM   64
#define TJ     64           // j-tile per block
#define TB     4            // b-values per block
#define NW     8            // waves per block (512 threads)
#define WI     (IN_F / NW)  // 128 i per wave (in-block split-K)

// Math: out[b,j] = relu(bias[j] + sum_i trunc(x[b,i] * K[i,j] / 256))
// Exact collapse of the reference's 4-round base-4 digit loop:
//   floor((floor(A/4)+B)/4) = floor((A+4B)/16) applied 4x; trunc is
//   odd-symmetric in sign(w), x >= 0. All intermediates are exact small
//   integers in fp32 -> bit-exact, order-independent.
//
// Structure notes (R1..R6):
//  - ~40 us of dur_us is fixed harness tax: 256 MiB ws poison fill at
//    ~6.6 TB/s, enqueued even when ws is unused. Untouchable.
//  - R6: split-K ACROSS blocks (2-kernel + 2MB ws, 73.3) replaced by
//    split-K INSIDE the block (8 waves x 128-i chunks, LDS tree reduce).
//    Same VALU work and wave-parallelism, but one dispatch instead of two
//    and no 4MB ws round-trip.
//  - bid encoding jt=bid&15: all 16 blocks sharing a K column-slab land on
//    XCD jt%8 (round-robin dispatch) -> each 256KB slab HBM-fetched once,
//    L2-served for the other 15 blocks.
//  - K loads wave-contiguous: 64 lanes x 4B = one 256B request.

__global__ __launch_bounds__(512) void fused_kernel(
    const float* __restrict__ x, const float* __restrict__ K,
    const float* __restrict__ bias, float* __restrict__ out)
{
    const int bid  = blockIdx.x;        // 256 blocks = 1 per CU
    const int jt   = bid & 15;          // 16 j-tiles of 64 (fast index -> XCD locality)
    const int bg   = bid >> 4;          // 16 b-groups of 4
    const int tid  = threadIdx.x;
    const int w    = tid >> 6;          // wave 0..7
    const int lane = tid & 63;
    const int j0   = jt * TJ;
    const int b0   = bg * TB;

    // x tile, pre-scaled by 1/256, layout [i][b] so the inner loop does one
    // broadcast ds_read_b128 per i. 16 KB; reused as psum after the loop.
    __shared__ float xs[IN_F * TB];

    // stage: bb = idx&3, ii = idx>>2 -> contiguous (conflict-free) LDS writes;
    // global side is 4 segments x 64B per wave request (tiny, 8 iters, L2-hot).
    for (int idx = tid; idx < IN_F * TB; idx += 512) {
        const int bb = idx & 3;
        const int ii = idx >> 2;
        xs[idx] = x[(b0 + bb) * IN_F + ii] * (1.0f / 256.0f);
    }
    __syncthreads();

    float acc0 = 0.f, acc1 = 0.f, acc2 = 0.f, acc3 = 0.f;
    const int i0 = w * WI;
    const float*  kp = K + (size_t)i0 * UNITS + j0 + lane;
    const float4* xp = (const float4*)&xs[i0 * TB];
#pragma unroll 8
    for (int i = 0; i < WI; ++i) {
        const float  k  = kp[(size_t)i * UNITS];   // wave-contiguous dword
        const float4 xv = xp[i];                   // broadcast b128
        acc0 += truncf(xv.x * k);
        acc1 += truncf(xv.y * k);
        acc2 += truncf(xv.z * k);
        acc3 += truncf(xv.w * k);
    }

    __syncthreads();                    // xs broadcast reads done; reuse as psum
    float* psum = xs;                   // [w][b][j] : w*256 + b*64 + j (8 KB)
    psum[w * 256 + 0 * 64 + lane] = acc0;
    psum[w * 256 + 1 * 64 + lane] = acc1;
    psum[w * 256 + 2 * 64 + lane] = acc2;
    psum[w * 256 + 3 * 64 + lane] = acc3;
    __syncthreads();

    // tree-reduce 8 wave-partials + bias + relu; threads 0..255 cover (b,j)
    if (tid < 256) {
        const int b = tid >> 6;
        const int j = tid & 63;
        float s = 0.f;
#pragma unroll
        for (int ww = 0; ww < NW; ++ww)
            s += psum[ww * 256 + b * 64 + j];      // conflict-free: lane-consecutive addrs
        s += bias[j0 + j];
        out[(b0 + b) * UNITS + j0 + j] = fmaxf(s, 0.f);
    }
}

extern "C" void kernel_launch(void* const* d_in, const int* in_sizes, int n_in,
                              void* d_out, int out_size, void* d_ws, size_t ws_size,
                              hipStream_t stream) {
    const float* x    = (const float*)d_in[0];  // (64, 1024)
    const float* K    = (const float*)d_in[1];  // (1024, 1024)
    const float* bias = (const float*)d_in[2];  // (1024,)
    // d_in[3] = bits (always 8)
    float* out = (float*)d_out;                 // (64, 1024)

    fused_kernel<<<256, 512, 0, stream>>>(x, K, bias, out);
}

// Round 2
// 67.229 us; speedup vs baseline: 1.0896x; 1.0375x over previous
//
#include <hip/hip_runtime.h>

// Problem constants (B=64, IN=1024, UNITS=1024, BITS=8)
#define IN_F   1024
#define UNITS  1024
#define BDIM   64
#define TJ     64           // j-tile per block
#define TB     4            // b-values per block
#define NW     16           // waves per block (1024 threads)
#define WI     (IN_F / NW)  // 64 i per wave (in-block split-K)

// Math: out[b,j] = relu(bias[j] + sum_i trunc(x[b,i] * K[i,j] / 256))
// Exact collapse of the reference's 4-round base-4 digit loop:
//   floor((floor(A/4)+B)/4) = floor((A+4B)/16) applied 4x; trunc is
//   odd-symmetric in sign(w), x >= 0. All intermediates are exact small
//   integers in fp32 -> bit-exact, order-independent.
//
// Structure notes (R1..R7):
//  - ~40 us of dur_us is fixed harness tax: 256 MiB ws poison fill at
//    ~6.6 TB/s, enqueued even when ws is unused. Untouchable.
//  - R6: one fused kernel (in-block split-K, LDS tree reduce) beat the
//    2-kernel split-K by 3.5 us (73.3 -> 69.7).
//  - R7: VALU floor is ~2.56 us (3 VALU ops/elem; packed-i16 or MFMA
//    reformulations all need per-iteration prep that eats the win).
//    Remaining levers: (a) wave-LOCAL x staging -> no pre-loop barrier;
//    (b) 16 waves/block = 4 waves/SIMD to hide K-load latency.
//  - bid encoding jt=bid&15: all 16 blocks sharing a K column-slab land on
//    XCD jt%8 (round-robin dispatch) -> slab HBM-fetched once, L2-served.
//  - K loads wave-contiguous: 64 lanes x 4B = one 256B request.

__global__ __launch_bounds__(1024) void fused_kernel(
    const float* __restrict__ x, const float* __restrict__ K,
    const float* __restrict__ bias, float* __restrict__ out)
{
    const int bid  = blockIdx.x;        // 256 blocks = 1 per CU
    const int jt   = bid & 15;          // 16 j-tiles of 64 (fast index -> XCD locality)
    const int bg   = bid >> 4;          // 16 b-groups of 4
    const int tid  = threadIdx.x;
    const int w    = tid >> 6;          // wave 0..15
    const int lane = tid & 63;
    const int j0   = jt * TJ;
    const int b0   = bg * TB;
    const int i0   = w * WI;

    // x tile, pre-scaled by 1/256, layout [i][b] so the inner loop does one
    // broadcast ds_read_b128 per i. Staged WAVE-LOCALLY (each wave fills and
    // reads only its own 1KB chunk) -> no barrier before the compute loop;
    // intra-wave ds ordering is handled by lgkmcnt.
    __shared__ float xs[IN_F * TB];     // 16 KB
    __shared__ float ps[NW * TB * TJ];  // 16 KB wave partials (separate: no race)

    for (int t = lane; t < WI * TB; t += 64) {
        const int bb = t & 3;
        const int ii = t >> 2;
        xs[i0 * TB + t] = x[(b0 + bb) * IN_F + i0 + ii] * (1.0f / 256.0f);
    }

    float acc0 = 0.f, acc1 = 0.f, acc2 = 0.f, acc3 = 0.f;
    const float*  kp = K + (size_t)i0 * UNITS + j0 + lane;
    const float4* xp = (const float4*)&xs[i0 * TB];
#pragma unroll 8
    for (int i = 0; i < WI; ++i) {
        const float  k  = kp[(size_t)i * UNITS];   // wave-contiguous dword
        const float4 xv = xp[i];                   // broadcast b128
        acc0 += truncf(xv.x * k);
        acc1 += truncf(xv.y * k);
        acc2 += truncf(xv.z * k);
        acc3 += truncf(xv.w * k);
    }

    // wave partials: ps[w][b][j] — conflict-free lane-consecutive writes
    ps[w * 256 + 0 * 64 + lane] = acc0;
    ps[w * 256 + 1 * 64 + lane] = acc1;
    ps[w * 256 + 2 * 64 + lane] = acc2;
    ps[w * 256 + 3 * 64 + lane] = acc3;
    __syncthreads();

    // tree-reduce 16 wave-partials + bias + relu; threads 0..255 cover (b,j)
    if (tid < 256) {
        const int b = tid >> 6;
        const int j = tid & 63;
        float s = 0.f;
#pragma unroll
        for (int ww = 0; ww < NW; ++ww)
            s += ps[ww * 256 + b * 64 + j];        // lane-consecutive: conflict-free
        s += bias[j0 + j];
        out[(b0 + b) * UNITS + j0 + j] = fmaxf(s, 0.f);
    }
}

extern "C" void kernel_launch(void* const* d_in, const int* in_sizes, int n_in,
                              void* d_out, int out_size, void* d_ws, size_t ws_size,
                              hipStream_t stream) {
    const float* x    = (const float*)d_in[0];  // (64, 1024)
    const float* K    = (const float*)d_in[1];  // (1024, 1024)
    const float* bias = (const float*)d_in[2];  // (1024,)
    // d_in[3] = bits (always 8)
    float* out = (float*)d_out;                 // (64, 1024)

    fused_kernel<<<256, 1024, 0, stream>>>(x, K, bias, out);
}